// Round 12
// baseline (279.167 us; speedup 1.0000x reference)
//
#include <hip/hip_runtime.h>
#include <hip/hip_fp16.h>
#include <cstdint>
#include <cstddef>

// ---------------------------------------------------------------------------
// GCN: 3x GraphConv(norm='both') + linear head, fp32 in/out.
// Round 12:
//  - agg: 4 nodes per wave, interleaved rounds (up to 8 independent gathers
//    in flight per wave). FETCH is at the compulsory per-XCD floor (82MB);
//    the lever is miss concurrency: 17G misses/s now vs 25G demonstrated.
//    Per-node loop body = proven round-8 code (fdot2 + reduce-scatter).
//  - dego NCO 40->64 (grid 320->512; was under-occupied at 1.25 blocks/CU).
//  - everything else frozen from round 11 (264.5us).
// ---------------------------------------------------------------------------

#define WG 256
static constexpr int NCHUNK = 512;   // edge chunks for dst bucketing
static constexpr int RW_SH  = 7;     // range width = 128 nodes (dst>>7)
static constexpr int RWID   = 1 << RW_SH;
static constexpr int BPRO   = 12512; // nodes per dego range (packed u16, 25KB)
static constexpr int NRO    = 8;     // dego ranges (8*12512 >= 100000)
static constexpr int NCO    = 64;    // edge chunks for dego histogram

typedef _Float16 half8 __attribute__((ext_vector_type(8)));
typedef _Float16 half2v __attribute__((ext_vector_type(2)));
typedef float f32x4 __attribute__((ext_vector_type(4)));

__device__ __forceinline__ int block_scan_excl(int v, int tid, int* sd, int& total) {
  sd[tid] = v;
  __syncthreads();
  for (int off = 1; off < 256; off <<= 1) {
    int t = (tid >= off) ? sd[tid - off] : 0;
    __syncthreads();
    sd[tid] += t;
    __syncthreads();
  }
  int incl = sd[tid];
  total = sd[255];
  __syncthreads();
  return incl - v;
}

// --- Pass A: per-chunk coarse histogram over dst ranges ---------------------
__global__ __launch_bounds__(WG) void coarse_hist_kernel(const int* __restrict__ dst,
                                                         int* __restrict__ cntA,
                                                         int NR, int E, int EPC) {
  __shared__ int cnt[1024];
  const int c = blockIdx.x, tid = threadIdx.x;
  for (int i = tid; i < NR; i += WG) cnt[i] = 0;
  __syncthreads();
  const int base = c * EPC;
  const int nv4 = EPC >> 2;
  const int4* d4 = (const int4*)(dst + base);
  for (int i = tid; i < nv4; i += WG) {
    const int e = base + (i << 2);
    if (e + 3 < E) {
      const int4 v = d4[i];
      atomicAdd(&cnt[v.x >> RW_SH], 1);
      atomicAdd(&cnt[v.y >> RW_SH], 1);
      atomicAdd(&cnt[v.z >> RW_SH], 1);
      atomicAdd(&cnt[v.w >> RW_SH], 1);
    } else {
      for (int j = 0; j < 4; ++j) {
        const int ee = e + j;
        if (ee < E) atomicAdd(&cnt[dst[ee] >> RW_SH], 1);
      }
    }
  }
  __syncthreads();
  for (int i = tid; i < NR; i += WG) cntA[i * NCHUNK + c] = cnt[i];
}

// --- Pass B1: per-range exclusive scan over the 512 chunks ------------------
__global__ __launch_bounds__(WG) void chunkscan_kernel(const int* __restrict__ cntA,
                                                       int* __restrict__ base_rel,
                                                       int* __restrict__ cntR) {
  __shared__ int sd[256];
  const int r = blockIdx.x, tid = threadIdx.x;
  const int row = r * NCHUNK;
  int t0, t1;
  const int v0 = cntA[row + tid];
  const int e0 = block_scan_excl(v0, tid, sd, t0);
  base_rel[row + tid] = e0;
  const int v1 = cntA[row + 256 + tid];
  const int e1 = block_scan_excl(v1, tid, sd, t1);
  base_rel[row + 256 + tid] = t0 + e1;
  if (tid == 0) cntR[r] = t0 + t1;
}

// --- Pass B2: exclusive scan over up to 1024 ranges -> rangeStart -----------
__global__ __launch_bounds__(WG) void rangescan_kernel(const int* __restrict__ cntR,
                                                       int* __restrict__ rangeStart,
                                                       int* __restrict__ rptr,
                                                       int NR, int N, int E) {
  __shared__ int sd[256];
  const int tid = threadIdx.x;
  int carry = 0;
  for (int base = 0; base < NR; base += 256) {
    const int idx = base + tid;
    const int v = (idx < NR) ? cntR[idx] : 0;
    int tot;
    const int e = block_scan_excl(v, tid, sd, tot);
    if (idx < NR) rangeStart[idx] = carry + e;
    carry += tot;
  }
  if (tid == 0) { rangeStart[NR] = E; rptr[N] = E; }
}

// --- Pass C: bucket scatter with LDS cursors, 4B packed entries -------------
__global__ __launch_bounds__(WG) void bucket_kernel(const int* __restrict__ src,
                                                    const int* __restrict__ dst,
                                                    const int* __restrict__ base_rel,
                                                    const int* __restrict__ rangeStart,
                                                    int* __restrict__ bucket,
                                                    int NR, int E, int EPC) {
  __shared__ int cur[1024];
  const int c = blockIdx.x, tid = threadIdx.x;
  for (int i = tid; i < NR; i += WG) cur[i] = rangeStart[i] + base_rel[i * NCHUNK + c];
  __syncthreads();
  const int base = c * EPC;
  const int nv4 = EPC >> 2;
  const int4* s4 = (const int4*)(src + base);
  const int4* d4 = (const int4*)(dst + base);
  for (int i = tid; i < nv4; i += WG) {
    const int e = base + (i << 2);
    if (e + 3 < E) {
      const int4 sv = s4[i];
      const int4 dv = d4[i];
      int p;
      p = atomicAdd(&cur[dv.x >> RW_SH], 1); bucket[p] = (sv.x << RW_SH) | (dv.x & (RWID - 1));
      p = atomicAdd(&cur[dv.y >> RW_SH], 1); bucket[p] = (sv.y << RW_SH) | (dv.y & (RWID - 1));
      p = atomicAdd(&cur[dv.z >> RW_SH], 1); bucket[p] = (sv.z << RW_SH) | (dv.z & (RWID - 1));
      p = atomicAdd(&cur[dv.w >> RW_SH], 1); bucket[p] = (sv.w << RW_SH) | (dv.w & (RWID - 1));
    } else {
      for (int j = 0; j < 4; ++j) {
        const int ee = e + j;
        if (ee < E) {
          const int s = src[ee], d = dst[ee];
          const int p = atomicAdd(&cur[d >> RW_SH], 1);
          bucket[p] = (s << RW_SH) | (d & (RWID - 1));
        }
      }
    }
  }
}

// --- Pass D: per-range CSR finalize (rptr, degi, esrc) ----------------------
__global__ __launch_bounds__(WG) void csr_kernel(const int* __restrict__ bucket,
                                                 const int* __restrict__ rangeStart,
                                                 int* __restrict__ rptr,
                                                 int* __restrict__ degi,
                                                 int* __restrict__ esrc, int N) {
  __shared__ int hist[RWID], sd[256];
  const int r = blockIdx.x, tid = threadIdx.x;
  const int s0 = rangeStart[r], s1 = rangeStart[r + 1];
  if (tid < RWID) hist[tid] = 0;
  __syncthreads();
  for (int e = s0 + tid; e < s1; e += WG) atomicAdd(&hist[bucket[e] & (RWID - 1)], 1);
  __syncthreads();
  const int v = (tid < RWID) ? hist[tid] : 0;
  int tot;
  const int excl = block_scan_excl(v, tid, sd, tot);
  const int node = (r << RW_SH) + tid;
  if (tid < RWID && node < N) { degi[node] = v; rptr[node] = s0 + excl; }
  if (tid < RWID) hist[tid] = s0 + excl;
  __syncthreads();
  for (int e = s0 + tid; e < s1; e += WG) {
    const int pk = bucket[e];
    const int p = atomicAdd(&hist[pk & (RWID - 1)], 1);
    esrc[p] = pk >> RW_SH;
  }
}

// --- dego: u16-packed privatized LDS histogram over src ---------------------
__global__ __launch_bounds__(WG) void dego_hist_kernel(const int* __restrict__ src,
                                                       int* __restrict__ slab,
                                                       int N, int E, int EPCO) {
  __shared__ int h[BPRO / 2];  // 25 KB, u16 pair per word
  const int rr = blockIdx.x / NCO, cc = blockIdx.x % NCO;
  const int tid = threadIdx.x;
  for (int i = tid; i < (BPRO >> 3); i += WG) ((int4*)h)[i] = make_int4(0, 0, 0, 0);
  __syncthreads();
  const int lo = rr * BPRO;
  const int base = cc * EPCO;
  const int nv4 = EPCO >> 2;
  const int4* s4 = (const int4*)(src + base);
  for (int i = tid; i < nv4; i += WG) {
    const int e = base + (i << 2);
    if (e + 3 < E) {
      const int4 v = s4[i];
      unsigned b;
      b = (unsigned)(v.x - lo); if (b < (unsigned)BPRO) atomicAdd((unsigned*)&h[b >> 1], 1u << ((b & 1) << 4));
      b = (unsigned)(v.y - lo); if (b < (unsigned)BPRO) atomicAdd((unsigned*)&h[b >> 1], 1u << ((b & 1) << 4));
      b = (unsigned)(v.z - lo); if (b < (unsigned)BPRO) atomicAdd((unsigned*)&h[b >> 1], 1u << ((b & 1) << 4));
      b = (unsigned)(v.w - lo); if (b < (unsigned)BPRO) atomicAdd((unsigned*)&h[b >> 1], 1u << ((b & 1) << 4));
    } else {
      for (int j = 0; j < 4; ++j) {
        const int ee = e + j;
        if (ee < E) {
          const unsigned b = (unsigned)(src[ee] - lo);
          if (b < (unsigned)BPRO) atomicAdd((unsigned*)&h[b >> 1], 1u << ((b & 1) << 4));
        }
      }
    }
  }
  __syncthreads();
  const int NW = N >> 1;               // N even
  const int wbase = lo >> 1;           // lo even (BPRO even)
  int* srow = slab + (size_t)cc * NW;
  for (int i = tid; i < (BPRO >> 3); i += WG) {
    const int wg = wbase + (i << 2);
    if (wg + 3 < NW) {
      ((int4*)(srow + wg))[0] = ((const int4*)h)[i];
    } else {
      for (int j = 0; j < 4; ++j)
        if (wg + j < NW) srow[wg + j] = h[(i << 2) + j];
    }
  }
}

__global__ __launch_bounds__(WG) void dego_reduce_inv_kernel(const int* __restrict__ slab,
                                                             const int* __restrict__ degi,
                                                             float* __restrict__ invo,
                                                             float* __restrict__ invi, int N) {
  const int NW = N >> 1;
  const int i = blockIdx.x * WG + threadIdx.x;  // node-pair index
  if (i >= NW) return;
  unsigned s = 0;
#pragma unroll
  for (int c = 0; c < NCO; ++c) s += (unsigned)slab[(size_t)c * NW + i];
  int d0 = (int)(s & 0xffffu); if (d0 < 1) d0 = 1;
  int d1 = (int)(s >> 16);     if (d1 < 1) d1 = 1;
  const int2 dd = *(const int2*)(degi + 2 * i);
  const int i0 = (dd.x < 1) ? 1 : dd.x;
  const int i1 = (dd.y < 1) ? 1 : dd.y;
  *(float2*)(invo + 2 * i) = make_float2(rsqrtf((float)d0), rsqrtf((float)d1));
  *(float2*)(invi + 2 * i) = make_float2(rsqrtf((float)i0), rsqrtf((float)i1));
}

// --- weight transpose+convert: WT[c][k] = (f16)W[k][c] ----------------------
__global__ __launch_bounds__(WG) void wtrans_kernel(const float* __restrict__ W0,
                                                    const float* __restrict__ W1,
                                                    const float* __restrict__ W2,
                                                    const float* __restrict__ Wl,
                                                    _Float16* __restrict__ T0,
                                                    _Float16* __restrict__ T1,
                                                    _Float16* __restrict__ T2,
                                                    _Float16* __restrict__ Tl) {
  const float* W; _Float16* T; int K;
  switch (blockIdx.x) {
    case 0: W = W0; T = T0; K = 128; break;
    case 1: W = W1; T = T1; K = 64; break;
    case 2: W = W2; T = T2; K = 64; break;
    default: W = Wl; T = Tl; K = 64; break;
  }
  for (int i = threadIdx.x; i < K * 64; i += WG) {
    const int k = i >> 6, c = i & 63;
    T[c * K + k] = (_Float16)W[i];
  }
}

// --- MFMA conv GEMM: hP[r][c] = f16( invo[r] * sum_k in[r][k] W[k][c] ) -----
template <int K, bool F16IN>
__global__ __launch_bounds__(256) void gemm_conv_mfma(const void* __restrict__ inv_,
                                                      const _Float16* __restrict__ WT,
                                                      const float* __restrict__ invo,
                                                      _Float16* __restrict__ hP, int N) {
  const int tid = threadIdx.x;
  const int w = tid >> 6, l = tid & 63;
  const int rowA = blockIdx.x * 64 + w * 16 + (l & 15);
  const int ar = (rowA < N) ? rowA : (N - 1);
  const int g8 = (l >> 4) * 8;

  f32x4 acc[4];
#pragma unroll
  for (int t = 0; t < 4; ++t) acc[t] = (f32x4){0.f, 0.f, 0.f, 0.f};

#pragma unroll
  for (int s = 0; s < K / 32; ++s) {
    const int kb = s * 32 + g8;
    half8 a;
    if constexpr (F16IN) {
      a = *(const half8*)((const _Float16*)inv_ + (size_t)ar * K + kb);
    } else {
      const float* in = (const float*)inv_;
      const float4 f0 = *(const float4*)(in + (size_t)ar * K + kb);
      const float4 f1 = *(const float4*)(in + (size_t)ar * K + kb + 4);
      a[0] = (_Float16)f0.x; a[1] = (_Float16)f0.y; a[2] = (_Float16)f0.z; a[3] = (_Float16)f0.w;
      a[4] = (_Float16)f1.x; a[5] = (_Float16)f1.y; a[6] = (_Float16)f1.z; a[7] = (_Float16)f1.w;
    }
#pragma unroll
    for (int t = 0; t < 4; ++t) {
      const half8 b = *(const half8*)(WT + (size_t)(16 * t + (l & 15)) * K + kb);
      acc[t] = __builtin_amdgcn_mfma_f32_16x16x32_f16(a, b, acc[t], 0, 0, 0);
    }
  }

  const int rbase = blockIdx.x * 64 + w * 16 + (l >> 4) * 4;
#pragma unroll
  for (int r = 0; r < 4; ++r) {
    const int row = rbase + r;
    if (row < N) {
      const float sc = invo[row];
#pragma unroll
      for (int t = 0; t < 4; ++t)
        hP[(size_t)row * 64 + 16 * t + (l & 15)] = (_Float16)(acc[t][r] * sc);
    }
  }
}

// --- MFMA head GEMM (f16 in): out[r][c] = sum_k in[r][k] W[k][c] + bias[c] --
__global__ __launch_bounds__(256) void gemm_head_mfma(const _Float16* __restrict__ in,
                                                      const _Float16* __restrict__ WT,
                                                      const float* __restrict__ bias,
                                                      float* __restrict__ out, int N) {
  constexpr int K = 64;
  const int tid = threadIdx.x;
  const int w = tid >> 6, l = tid & 63;
  const int rowA = blockIdx.x * 64 + w * 16 + (l & 15);
  const int ar = (rowA < N) ? rowA : (N - 1);
  const int g8 = (l >> 4) * 8;

  f32x4 acc[4];
#pragma unroll
  for (int t = 0; t < 4; ++t) acc[t] = (f32x4){0.f, 0.f, 0.f, 0.f};

#pragma unroll
  for (int s = 0; s < K / 32; ++s) {
    const int kb = s * 32 + g8;
    const half8 a = *(const half8*)(in + (size_t)ar * K + kb);
#pragma unroll
    for (int t = 0; t < 4; ++t) {
      const half8 b = *(const half8*)(WT + (size_t)(16 * t + (l & 15)) * K + kb);
      acc[t] = __builtin_amdgcn_mfma_f32_16x16x32_f16(a, b, acc[t], 0, 0, 0);
    }
  }

  const int rbase = blockIdx.x * 64 + w * 16 + (l >> 4) * 4;
#pragma unroll
  for (int r = 0; r < 4; ++r) {
    const int row = rbase + r;
    if (row < N) {
#pragma unroll
      for (int t = 0; t < 4; ++t) {
        const int c = 16 * t + (l & 15);
        out[(size_t)row * 64 + c] = acc[t][r] + bias[c];
      }
    }
  }
}

// --- reduce-scatter butterfly over 8 edge slots (static indices only) -------
__device__ __forceinline__ float reduce_scatter8(const float* acc, int g) {
  const bool gb0 = (g & 1) != 0;
  const float s0 = gb0 ? acc[0] : acc[1];
  const float s1 = gb0 ? acc[2] : acc[3];
  const float s2 = gb0 ? acc[4] : acc[5];
  const float s3 = gb0 ? acc[6] : acc[7];
  const float k0 = (gb0 ? acc[1] : acc[0]) + __shfl_xor(s0, 8);
  const float k1 = (gb0 ? acc[3] : acc[2]) + __shfl_xor(s1, 8);
  const float k2 = (gb0 ? acc[5] : acc[4]) + __shfl_xor(s2, 8);
  const float k3 = (gb0 ? acc[7] : acc[6]) + __shfl_xor(s3, 8);
  const bool gb1 = (g & 2) != 0;
  const float t0 = gb1 ? k0 : k1;
  const float t1 = gb1 ? k2 : k3;
  const float m0 = (gb1 ? k1 : k0) + __shfl_xor(t0, 16);
  const float m1 = (gb1 ? k3 : k2) + __shfl_xor(t1, 16);
  const bool gb2 = (g & 4) != 0;
  const float u0 = gb2 ? m0 : m1;
  return (gb2 ? m1 : m0) + __shfl_xor(u0, 32);
}

// --- CSR gather aggregation, 8 lanes per row, 4 NODES PER WAVE ---------------
// lane = 8*g + f8. Per interleaved round, the wave issues the conditional
// 16-edge gathers for all 4 nodes back-to-back (up to 8 independent b128
// gathers in flight), then consumes via fdot2. Per-node logic = round-8.
__global__ __launch_bounds__(256) void agg_kernel4(const _Float16* __restrict__ hp,
                                                   const int* __restrict__ rptr,
                                                   const int* __restrict__ esrc,
                                                   const float* __restrict__ invin,
                                                   const float* __restrict__ bias,
                                                   _Float16* __restrict__ out, int N,
                                                   int apply_elu) {
  const int wv = (blockIdx.x * 256 + threadIdx.x) >> 6;  // wave id
  const int lane = threadIdx.x & 63;
  const int g = lane >> 3;     // edge slot 0..7
  const int f8 = lane & 7;     // feature octet
  const int nb = wv * 4;       // first node of this wave
  if (nb >= N) return;
  const int f = f8 * 8 + g;
  const float bv = bias[f];

  // node ranges, clamped so nodes >= N come out empty (lo == hi == rptr[N])
  const int i1 = (nb + 1 < N) ? nb + 1 : N;
  const int i2 = (nb + 2 < N) ? nb + 2 : N;
  const int i3 = (nb + 3 < N) ? nb + 3 : N;
  const int i4 = (nb + 4 < N) ? nb + 4 : N;
  int lo0 = rptr[nb], lo1 = rptr[i1], lo2 = rptr[i2], lo3 = rptr[i3];
  const int hi0 = lo1, hi1 = lo2, hi2 = lo3, hi3 = rptr[i4];

  float acc0[8] = {0}, acc1[8] = {0}, acc2[8] = {0}, acc3[8] = {0};

#if __has_builtin(__builtin_amdgcn_fdot2)
  const half2v one2 = {(_Float16)1.0f, (_Float16)1.0f};
#define ACCPAIR(A_, X_, Y_) do { _Pragma("unroll") \
  for (int k = 0; k < 8; ++k) { half2v p; p[0] = X_[k]; p[1] = Y_[k]; \
    A_[k] = __builtin_amdgcn_fdot2(p, one2, A_[k], false); } } while (0)
#else
#define ACCPAIR(A_, X_, Y_) do { _Pragma("unroll") \
  for (int k = 0; k < 8; ++k) A_[k] += (float)X_[k] + (float)Y_[k]; } while (0)
#endif
#define ACCONE(A_, X_) do { _Pragma("unroll") \
  for (int k = 0; k < 8; ++k) A_[k] += (float)X_[k]; } while (0)
#define GPAIR(lo_, XA_, XB_) do { \
  const int sA_ = esrc[(lo_) + g], sB_ = esrc[(lo_) + 8 + g]; \
  XA_ = *(const half8*)(hp + (size_t)sA_ * 64 + f8 * 8); \
  XB_ = *(const half8*)(hp + (size_t)sB_ * 64 + f8 * 8); } while (0)

  // interleaved 16-edge rounds: issue all active nodes' gathers, then consume
  while (true) {
    const bool a0 = lo0 + 16 <= hi0;
    const bool a1 = lo1 + 16 <= hi1;
    const bool a2 = lo2 + 16 <= hi2;
    const bool a3 = lo3 + 16 <= hi3;
    if (!(a0 | a1 | a2 | a3)) break;
    half8 A0, B0, A1, B1, A2, B2, A3, B3;
    if (a0) GPAIR(lo0, A0, B0);
    if (a1) GPAIR(lo1, A1, B1);
    if (a2) GPAIR(lo2, A2, B2);
    if (a3) GPAIR(lo3, A3, B3);
    if (a0) { ACCPAIR(acc0, A0, B0); lo0 += 16; }
    if (a1) { ACCPAIR(acc1, A1, B1); lo1 += 16; }
    if (a2) { ACCPAIR(acc2, A2, B2); lo2 += 16; }
    if (a3) { ACCPAIR(acc3, A3, B3); lo3 += 16; }
  }

  // one 8-edge step per node (issue-all then consume)
  {
    const bool c0 = lo0 + 8 <= hi0;
    const bool c1 = lo1 + 8 <= hi1;
    const bool c2 = lo2 + 8 <= hi2;
    const bool c3 = lo3 + 8 <= hi3;
    half8 A0, A1, A2, A3;
    if (c0) { const int s = esrc[lo0 + g]; A0 = *(const half8*)(hp + (size_t)s * 64 + f8 * 8); }
    if (c1) { const int s = esrc[lo1 + g]; A1 = *(const half8*)(hp + (size_t)s * 64 + f8 * 8); }
    if (c2) { const int s = esrc[lo2 + g]; A2 = *(const half8*)(hp + (size_t)s * 64 + f8 * 8); }
    if (c3) { const int s = esrc[lo3 + g]; A3 = *(const half8*)(hp + (size_t)s * 64 + f8 * 8); }
    if (c0) { ACCONE(acc0, A0); lo0 += 8; }
    if (c1) { ACCONE(acc1, A1); lo1 += 8; }
    if (c2) { ACCONE(acc2, A2); lo2 += 8; }
    if (c3) { ACCONE(acc3, A3); lo3 += 8; }
  }

  // masked tails (rem 1..7 edges per node)
#define TAIL(lo_, hi_, A_) do { if ((lo_) < (hi_)) { \
    const int rem_ = (hi_) - (lo_); \
    int idx_ = (lo_) + g; if (idx_ > (hi_) - 1) idx_ = (hi_) - 1; \
    const int s_ = esrc[idx_]; \
    const half8 hv_ = *(const half8*)(hp + (size_t)s_ * 64 + f8 * 8); \
    const float m_ = (g < rem_) ? 1.f : 0.f; \
    _Pragma("unroll") for (int k = 0; k < 8; ++k) A_[k] = fmaf(m_, (float)hv_[k], A_[k]); } } while (0)
  TAIL(lo0, hi0, acc0);
  TAIL(lo1, hi1, acc1);
  TAIL(lo2, hi2, acc2);
  TAIL(lo3, hi3, acc3);
#undef TAIL
#undef GPAIR
#undef ACCONE
#undef ACCPAIR

  // reduce + epilogue per node; lane (g,f8) owns feature f = f8*8+g
#define EPI(J_, A_) do { const int node_ = nb + (J_); if (node_ < N) { \
    float v_ = reduce_scatter8(A_, g) * invin[node_] + bv; \
    if (apply_elu) v_ = (v_ > 0.f) ? v_ : (__expf(v_) - 1.0f); \
    out[(size_t)node_ * 64 + f] = (_Float16)v_; } } while (0)
  EPI(0, acc0);
  EPI(1, acc1);
  EPI(2, acc2);
  EPI(3, acc3);
#undef EPI
}

extern "C" void kernel_launch(void* const* d_in, const int* in_sizes, int n_in,
                              void* d_out, int out_size, void* d_ws, size_t ws_size,
                              hipStream_t stream) {
  const float* x  = (const float*)d_in[0];
  const int*   src = (const int*)d_in[1];
  const int*   dst = (const int*)d_in[2];
  const float* W0 = (const float*)d_in[3];
  const float* b0 = (const float*)d_in[4];
  const float* W1 = (const float*)d_in[5];
  const float* b1 = (const float*)d_in[6];
  const float* W2 = (const float*)d_in[7];
  const float* b2 = (const float*)d_in[8];
  const float* Wl = (const float*)d_in[9];
  const float* bl = (const float*)d_in[10];

  const int N = in_sizes[0] / 128;
  const int E = in_sizes[1];
  const int NR = (N + RWID - 1) >> RW_SH;
  const int EPC = (((E + NCHUNK - 1) / NCHUNK) + 3) & ~3;
  const int EPCO = (((E + NCO - 1) / NCO) + 3) & ~3;

  int* wsp = (int*)d_ws;
  size_t off = 0;
  auto alloc = [&](size_t n) -> int* {   // 256B-aligned regions
    int* p = wsp + off;
    off += (n + 63) & ~(size_t)63;
    return p;
  };
  int*      degi       = alloc(N);
  float*    invo       = (float*)alloc(N);
  float*    invi       = (float*)alloc(N);
  int*      rptr       = alloc((size_t)N + 1);
  int*      esrc       = alloc(E);
  int*      cntA       = alloc((size_t)NR * NCHUNK);
  int*      base_rel   = alloc((size_t)NR * NCHUNK);
  int*      cntR       = alloc(NR);
  int*      rangeStart = alloc((size_t)NR + 1);
  int*      bucket     = alloc(E);
  int*      slab       = alloc((size_t)NCO * (N >> 1));  // u16-packed
  _Float16* hP         = (_Float16*)alloc((size_t)N * 32);  // N x 64 f16
  _Float16* hA         = (_Float16*)alloc((size_t)N * 32);  // N x 64 f16
  _Float16* WT0        = (_Float16*)alloc(64 * 128 / 2);
  _Float16* WT1        = (_Float16*)alloc(64 * 64 / 2);
  _Float16* WT2        = (_Float16*)alloc(64 * 64 / 2);
  _Float16* WTl        = (_Float16*)alloc(64 * 64 / 2);
  (void)ws_size; (void)n_in; (void)out_size;

  const int gAgg = (N + 15) / 16;        // 4 waves x 4 nodes per block
  const int gGemm = (N + 63) / 64;
  const int gRed = ((N >> 1) + WG - 1) / WG;

  // CSR-by-dst build (atomic-free at global scope)
  coarse_hist_kernel<<<NCHUNK, WG, 0, stream>>>(dst, cntA, NR, E, EPC);
  chunkscan_kernel<<<NR, WG, 0, stream>>>(cntA, base_rel, cntR);
  rangescan_kernel<<<1, WG, 0, stream>>>(cntR, rangeStart, rptr, NR, N, E);
  bucket_kernel<<<NCHUNK, WG, 0, stream>>>(src, dst, base_rel, rangeStart, bucket, NR, E, EPC);
  csr_kernel<<<NR, WG, 0, stream>>>(bucket, rangeStart, rptr, degi, esrc, N);

  // out-degree via u16-packed LDS histograms + fused inv; weight transposes
  dego_hist_kernel<<<NRO * NCO, WG, 0, stream>>>(src, slab, N, E, EPCO);
  dego_reduce_inv_kernel<<<gRed, WG, 0, stream>>>(slab, degi, invo, invi, N);
  wtrans_kernel<<<4, WG, 0, stream>>>(W0, W1, W2, Wl, WT0, WT1, WT2, WTl);

  // layer 0: (x@W0)*invo -> agg -> *invi+b0 -> elu
  gemm_conv_mfma<128, false><<<gGemm, 256, 0, stream>>>(x, WT0, invo, hP, N);
  agg_kernel4<<<gAgg, 256, 0, stream>>>(hP, rptr, esrc, invi, b0, hA, N, 1);
  // layer 1
  gemm_conv_mfma<64, true><<<gGemm, 256, 0, stream>>>(hA, WT1, invo, hP, N);
  agg_kernel4<<<gAgg, 256, 0, stream>>>(hP, rptr, esrc, invi, b1, hA, N, 1);
  // layer 2 (+ fused elu ahead of the linear head)
  gemm_conv_mfma<64, true><<<gGemm, 256, 0, stream>>>(hA, WT2, invo, hP, N);
  agg_kernel4<<<gAgg, 256, 0, stream>>>(hP, rptr, esrc, invi, b2, hA, N, 1);
  // head: elu(h2) @ Wl + bl
  gemm_head_mfma<<<gGemm, 256, 0, stream>>>(hA, WTl, bl, (float*)d_out, N);
}

// Round 13
// 242.899 us; speedup vs baseline: 1.1493x; 1.1493x over previous
//
#include <hip/hip_runtime.h>
#include <hip/hip_fp16.h>
#include <cstdint>
#include <cstddef>

// ---------------------------------------------------------------------------
// GCN: 3x GraphConv(norm='both') + linear head, fp32 in/out.
// Round 13 = round-11 compute path (agg frozen at round-8 form: 41G
// line-touches/s = L2 request ceiling; FETCH 82MB = compulsory floor) +
// setup-chain consolidation:
//  - K1: coarse_hist || dego_hist || wtrans  (one launch, blockIdx dispatch)
//  - K2: chunkscan || dego_reduce->invo
//  - invi computed inside csr_kernel (degi buffer + extra pass deleted)
// 15 launches -> 12; dego_hist overlaps coarse_hist instead of serializing.
// ---------------------------------------------------------------------------

#define WG 256
static constexpr int NCHUNK = 512;   // edge chunks for dst bucketing
static constexpr int RW_SH  = 7;     // range width = 128 nodes (dst>>7)
static constexpr int RWID   = 1 << RW_SH;
static constexpr int BPRO   = 12512; // nodes per dego range (packed u16, 25KB)
static constexpr int NRO    = 8;     // dego ranges (8*12512 >= 100000)
static constexpr int NCO    = 64;    // edge chunks for dego histogram

typedef _Float16 half8 __attribute__((ext_vector_type(8)));
typedef _Float16 half2v __attribute__((ext_vector_type(2)));
typedef float f32x4 __attribute__((ext_vector_type(4)));

__device__ __forceinline__ int block_scan_excl(int v, int tid, int* sd, int& total) {
  sd[tid] = v;
  __syncthreads();
  for (int off = 1; off < 256; off <<= 1) {
    int t = (tid >= off) ? sd[tid - off] : 0;
    __syncthreads();
    sd[tid] += t;
    __syncthreads();
  }
  int incl = sd[tid];
  total = sd[255];
  __syncthreads();
  return incl - v;
}

// --- K1: coarse_hist (dst) || dego_hist (src) || wtrans ---------------------
__global__ __launch_bounds__(WG) void setup1_kernel(const int* __restrict__ src,
                                                    const int* __restrict__ dst,
                                                    int* __restrict__ cntA,
                                                    int* __restrict__ slab,
                                                    const float* __restrict__ W0,
                                                    const float* __restrict__ W1,
                                                    const float* __restrict__ W2,
                                                    const float* __restrict__ Wl,
                                                    _Float16* __restrict__ T0,
                                                    _Float16* __restrict__ T1,
                                                    _Float16* __restrict__ T2,
                                                    _Float16* __restrict__ Tl,
                                                    int NR, int N, int E, int EPC, int EPCO) {
  __shared__ int smem[BPRO / 2];   // 25KB union: cnt[<=1024] / h[BPRO/2]
  const int b = blockIdx.x, tid = threadIdx.x;

  if (b < NCHUNK) {
    // ---- coarse histogram of dst ranges for chunk b ----
    int* cnt = smem;
    for (int i = tid; i < NR; i += WG) cnt[i] = 0;
    __syncthreads();
    const int base = b * EPC;
    const int nv4 = EPC >> 2;
    const int4* d4 = (const int4*)(dst + base);
    for (int i = tid; i < nv4; i += WG) {
      const int e = base + (i << 2);
      if (e + 3 < E) {
        const int4 v = d4[i];
        atomicAdd(&cnt[v.x >> RW_SH], 1);
        atomicAdd(&cnt[v.y >> RW_SH], 1);
        atomicAdd(&cnt[v.z >> RW_SH], 1);
        atomicAdd(&cnt[v.w >> RW_SH], 1);
      } else {
        for (int j = 0; j < 4; ++j) {
          const int ee = e + j;
          if (ee < E) atomicAdd(&cnt[dst[ee] >> RW_SH], 1);
        }
      }
    }
    __syncthreads();
    for (int i = tid; i < NR; i += WG) cntA[i * NCHUNK + b] = cnt[i];
    return;
  }

  if (b < NCHUNK + NRO * NCO) {
    // ---- u16-packed dego histogram ----
    int* h = smem;
    const int bb = b - NCHUNK;
    const int rr = bb / NCO, cc = bb % NCO;
    for (int i = tid; i < (BPRO >> 3); i += WG) ((int4*)h)[i] = make_int4(0, 0, 0, 0);
    __syncthreads();
    const int lo = rr * BPRO;
    const int base = cc * EPCO;
    const int nv4 = EPCO >> 2;
    const int4* s4 = (const int4*)(src + base);
    for (int i = tid; i < nv4; i += WG) {
      const int e = base + (i << 2);
      if (e + 3 < E) {
        const int4 v = s4[i];
        unsigned x;
        x = (unsigned)(v.x - lo); if (x < (unsigned)BPRO) atomicAdd((unsigned*)&h[x >> 1], 1u << ((x & 1) << 4));
        x = (unsigned)(v.y - lo); if (x < (unsigned)BPRO) atomicAdd((unsigned*)&h[x >> 1], 1u << ((x & 1) << 4));
        x = (unsigned)(v.z - lo); if (x < (unsigned)BPRO) atomicAdd((unsigned*)&h[x >> 1], 1u << ((x & 1) << 4));
        x = (unsigned)(v.w - lo); if (x < (unsigned)BPRO) atomicAdd((unsigned*)&h[x >> 1], 1u << ((x & 1) << 4));
      } else {
        for (int j = 0; j < 4; ++j) {
          const int ee = e + j;
          if (ee < E) {
            const unsigned x = (unsigned)(src[ee] - lo);
            if (x < (unsigned)BPRO) atomicAdd((unsigned*)&h[x >> 1], 1u << ((x & 1) << 4));
          }
        }
      }
    }
    __syncthreads();
    const int NW = N >> 1;
    const int wbase = lo >> 1;
    int* srow = slab + (size_t)cc * NW;
    for (int i = tid; i < (BPRO >> 3); i += WG) {
      const int wg = wbase + (i << 2);
      if (wg + 3 < NW) {
        ((int4*)(srow + wg))[0] = ((const int4*)h)[i];
      } else {
        for (int j = 0; j < 4; ++j)
          if (wg + j < NW) srow[wg + j] = h[(i << 2) + j];
      }
    }
    return;
  }

  // ---- wtrans: WT[c][k] = (f16)W[k][c] ----
  const float* W; _Float16* T; int K;
  switch (b - (NCHUNK + NRO * NCO)) {
    case 0: W = W0; T = T0; K = 128; break;
    case 1: W = W1; T = T1; K = 64; break;
    case 2: W = W2; T = T2; K = 64; break;
    default: W = Wl; T = Tl; K = 64; break;
  }
  for (int i = tid; i < K * 64; i += WG) {
    const int k = i >> 6, c = i & 63;
    T[c * K + k] = (_Float16)W[i];
  }
}

// --- K2: chunkscan || dego_reduce -> invo ------------------------------------
__global__ __launch_bounds__(WG) void setup2_kernel(const int* __restrict__ cntA,
                                                    int* __restrict__ base_rel,
                                                    int* __restrict__ cntR,
                                                    const int* __restrict__ slab,
                                                    float* __restrict__ invo,
                                                    int NR, int N) {
  __shared__ int sd[256];
  const int b = blockIdx.x, tid = threadIdx.x;

  if (b < NR) {
    // ---- per-range exclusive scan over the 512 chunks ----
    const int row = b * NCHUNK;
    int t0, t1;
    const int v0 = cntA[row + tid];
    const int e0 = block_scan_excl(v0, tid, sd, t0);
    base_rel[row + tid] = e0;
    const int v1 = cntA[row + 256 + tid];
    const int e1 = block_scan_excl(v1, tid, sd, t1);
    base_rel[row + 256 + tid] = t0 + e1;
    if (tid == 0) cntR[b] = t0 + t1;
    return;
  }

  // ---- dego reduce -> invo (node pairs) ----
  const int NW = N >> 1;
  const int i = (b - NR) * WG + tid;
  if (i >= NW) return;
  unsigned s = 0;
#pragma unroll
  for (int c = 0; c < NCO; ++c) s += (unsigned)slab[(size_t)c * NW + i];
  int d0 = (int)(s & 0xffffu); if (d0 < 1) d0 = 1;
  int d1 = (int)(s >> 16);     if (d1 < 1) d1 = 1;
  *(float2*)(invo + 2 * i) = make_float2(rsqrtf((float)d0), rsqrtf((float)d1));
}

// --- K3: exclusive scan over up to 1024 ranges -> rangeStart ----------------
__global__ __launch_bounds__(WG) void rangescan_kernel(const int* __restrict__ cntR,
                                                       int* __restrict__ rangeStart,
                                                       int* __restrict__ rptr,
                                                       int NR, int N, int E) {
  __shared__ int sd[256];
  const int tid = threadIdx.x;
  int carry = 0;
  for (int base = 0; base < NR; base += 256) {
    const int idx = base + tid;
    const int v = (idx < NR) ? cntR[idx] : 0;
    int tot;
    const int e = block_scan_excl(v, tid, sd, tot);
    if (idx < NR) rangeStart[idx] = carry + e;
    carry += tot;
  }
  if (tid == 0) { rangeStart[NR] = E; rptr[N] = E; }
}

// --- K4: bucket scatter with LDS cursors, 4B packed entries -----------------
__global__ __launch_bounds__(WG) void bucket_kernel(const int* __restrict__ src,
                                                    const int* __restrict__ dst,
                                                    const int* __restrict__ base_rel,
                                                    const int* __restrict__ rangeStart,
                                                    int* __restrict__ bucket,
                                                    int NR, int E, int EPC) {
  __shared__ int cur[1024];
  const int c = blockIdx.x, tid = threadIdx.x;
  for (int i = tid; i < NR; i += WG) cur[i] = rangeStart[i] + base_rel[i * NCHUNK + c];
  __syncthreads();
  const int base = c * EPC;
  const int nv4 = EPC >> 2;
  const int4* s4 = (const int4*)(src + base);
  const int4* d4 = (const int4*)(dst + base);
  for (int i = tid; i < nv4; i += WG) {
    const int e = base + (i << 2);
    if (e + 3 < E) {
      const int4 sv = s4[i];
      const int4 dv = d4[i];
      int p;
      p = atomicAdd(&cur[dv.x >> RW_SH], 1); bucket[p] = (sv.x << RW_SH) | (dv.x & (RWID - 1));
      p = atomicAdd(&cur[dv.y >> RW_SH], 1); bucket[p] = (sv.y << RW_SH) | (dv.y & (RWID - 1));
      p = atomicAdd(&cur[dv.z >> RW_SH], 1); bucket[p] = (sv.z << RW_SH) | (dv.z & (RWID - 1));
      p = atomicAdd(&cur[dv.w >> RW_SH], 1); bucket[p] = (sv.w << RW_SH) | (dv.w & (RWID - 1));
    } else {
      for (int j = 0; j < 4; ++j) {
        const int ee = e + j;
        if (ee < E) {
          const int s = src[ee], d = dst[ee];
          const int p = atomicAdd(&cur[d >> RW_SH], 1);
          bucket[p] = (s << RW_SH) | (d & (RWID - 1));
        }
      }
    }
  }
}

// --- K5: per-range CSR finalize (rptr, invi, esrc) ---------------------------
__global__ __launch_bounds__(WG) void csr_kernel(const int* __restrict__ bucket,
                                                 const int* __restrict__ rangeStart,
                                                 int* __restrict__ rptr,
                                                 float* __restrict__ invi,
                                                 int* __restrict__ esrc, int N) {
  __shared__ int hist[RWID], sd[256];
  const int r = blockIdx.x, tid = threadIdx.x;
  const int s0 = rangeStart[r], s1 = rangeStart[r + 1];
  if (tid < RWID) hist[tid] = 0;
  __syncthreads();
  for (int e = s0 + tid; e < s1; e += WG) atomicAdd(&hist[bucket[e] & (RWID - 1)], 1);
  __syncthreads();
  const int v = (tid < RWID) ? hist[tid] : 0;
  int tot;
  const int excl = block_scan_excl(v, tid, sd, tot);
  const int node = (r << RW_SH) + tid;
  if (tid < RWID && node < N) {
    rptr[node] = s0 + excl;
    invi[node] = rsqrtf((float)((v < 1) ? 1 : v));
  }
  if (tid < RWID) hist[tid] = s0 + excl;
  __syncthreads();
  for (int e = s0 + tid; e < s1; e += WG) {
    const int pk = bucket[e];
    const int p = atomicAdd(&hist[pk & (RWID - 1)], 1);
    esrc[p] = pk >> RW_SH;
  }
}

// --- MFMA conv GEMM: hP[r][c] = f16( invo[r] * sum_k in[r][k] W[k][c] ) -----
template <int K, bool F16IN>
__global__ __launch_bounds__(256) void gemm_conv_mfma(const void* __restrict__ inv_,
                                                      const _Float16* __restrict__ WT,
                                                      const float* __restrict__ invo,
                                                      _Float16* __restrict__ hP, int N) {
  const int tid = threadIdx.x;
  const int w = tid >> 6, l = tid & 63;
  const int rowA = blockIdx.x * 64 + w * 16 + (l & 15);
  const int ar = (rowA < N) ? rowA : (N - 1);
  const int g8 = (l >> 4) * 8;

  f32x4 acc[4];
#pragma unroll
  for (int t = 0; t < 4; ++t) acc[t] = (f32x4){0.f, 0.f, 0.f, 0.f};

#pragma unroll
  for (int s = 0; s < K / 32; ++s) {
    const int kb = s * 32 + g8;
    half8 a;
    if constexpr (F16IN) {
      a = *(const half8*)((const _Float16*)inv_ + (size_t)ar * K + kb);
    } else {
      const float* in = (const float*)inv_;
      const float4 f0 = *(const float4*)(in + (size_t)ar * K + kb);
      const float4 f1 = *(const float4*)(in + (size_t)ar * K + kb + 4);
      a[0] = (_Float16)f0.x; a[1] = (_Float16)f0.y; a[2] = (_Float16)f0.z; a[3] = (_Float16)f0.w;
      a[4] = (_Float16)f1.x; a[5] = (_Float16)f1.y; a[6] = (_Float16)f1.z; a[7] = (_Float16)f1.w;
    }
#pragma unroll
    for (int t = 0; t < 4; ++t) {
      const half8 b = *(const half8*)(WT + (size_t)(16 * t + (l & 15)) * K + kb);
      acc[t] = __builtin_amdgcn_mfma_f32_16x16x32_f16(a, b, acc[t], 0, 0, 0);
    }
  }

  const int rbase = blockIdx.x * 64 + w * 16 + (l >> 4) * 4;
#pragma unroll
  for (int r = 0; r < 4; ++r) {
    const int row = rbase + r;
    if (row < N) {
      const float sc = invo[row];
#pragma unroll
      for (int t = 0; t < 4; ++t)
        hP[(size_t)row * 64 + 16 * t + (l & 15)] = (_Float16)(acc[t][r] * sc);
    }
  }
}

// --- MFMA head GEMM (f16 in): out[r][c] = sum_k in[r][k] W[k][c] + bias[c] --
__global__ __launch_bounds__(256) void gemm_head_mfma(const _Float16* __restrict__ in,
                                                      const _Float16* __restrict__ WT,
                                                      const float* __restrict__ bias,
                                                      float* __restrict__ out, int N) {
  constexpr int K = 64;
  const int tid = threadIdx.x;
  const int w = tid >> 6, l = tid & 63;
  const int rowA = blockIdx.x * 64 + w * 16 + (l & 15);
  const int ar = (rowA < N) ? rowA : (N - 1);
  const int g8 = (l >> 4) * 8;

  f32x4 acc[4];
#pragma unroll
  for (int t = 0; t < 4; ++t) acc[t] = (f32x4){0.f, 0.f, 0.f, 0.f};

#pragma unroll
  for (int s = 0; s < K / 32; ++s) {
    const int kb = s * 32 + g8;
    const half8 a = *(const half8*)(in + (size_t)ar * K + kb);
#pragma unroll
    for (int t = 0; t < 4; ++t) {
      const half8 b = *(const half8*)(WT + (size_t)(16 * t + (l & 15)) * K + kb);
      acc[t] = __builtin_amdgcn_mfma_f32_16x16x32_f16(a, b, acc[t], 0, 0, 0);
    }
  }

  const int rbase = blockIdx.x * 64 + w * 16 + (l >> 4) * 4;
#pragma unroll
  for (int r = 0; r < 4; ++r) {
    const int row = rbase + r;
    if (row < N) {
#pragma unroll
      for (int t = 0; t < 4; ++t) {
        const int c = 16 * t + (l & 15);
        out[(size_t)row * 64 + c] = acc[t][r] + bias[c];
      }
    }
  }
}

// --- CSR gather aggregation, 8 lanes per row (round-8 form, frozen) ---------
// At the L2 request ceiling (~41G line-touches/s); FETCH at compulsory floor.
__global__ __launch_bounds__(256) void agg_kernel(const _Float16* __restrict__ hp,
                                                  const int* __restrict__ rptr,
                                                  const int* __restrict__ esrc,
                                                  const float* __restrict__ invin,
                                                  const float* __restrict__ bias,
                                                  _Float16* __restrict__ out, int N,
                                                  int apply_elu) {
  const int w = (blockIdx.x * 256 + threadIdx.x) >> 6;  // one wave per dst node
  const int lane = threadIdx.x & 63;
  const int g = lane >> 3;     // edge slot 0..7
  const int f8 = lane & 7;     // feature octet
  if (w >= N) return;
  const int e0 = rptr[w];
  const int e1 = rptr[w + 1];
  const int f = f8 * 8 + g;
  const float vi = invin[w];        // hoisted off the epilogue dep chain
  const float bv = bias[f];

  float acc[8];
#pragma unroll
  for (int k = 0; k < 8; ++k) acc[k] = 0.f;

  int e = e0;
  for (; e + 16 <= e1; e += 16) {   // 2 gathers in flight, fdot2 accumulate
    const int sA = esrc[e + g];
    const int sB = esrc[e + 8 + g];
    const half8 hA8 = *(const half8*)(hp + (size_t)sA * 64 + f8 * 8);
    const half8 hB8 = *(const half8*)(hp + (size_t)sB * 64 + f8 * 8);
#if __has_builtin(__builtin_amdgcn_fdot2)
    const half2v one2 = {(_Float16)1.0f, (_Float16)1.0f};
#pragma unroll
    for (int k = 0; k < 8; ++k) {
      half2v p; p[0] = hA8[k]; p[1] = hB8[k];
      acc[k] = __builtin_amdgcn_fdot2(p, one2, acc[k], false);
    }
#else
#pragma unroll
    for (int k = 0; k < 8; ++k) acc[k] += (float)hA8[k] + (float)hB8[k];
#endif
  }
  for (; e + 8 <= e1; e += 8) {
    const int s = esrc[e + g];
    const half8 hv = *(const half8*)(hp + (size_t)s * 64 + f8 * 8);
#pragma unroll
    for (int k = 0; k < 8; ++k) acc[k] += (float)hv[k];
  }
  if (e < e1) {                      // masked tail group
    const int rem = e1 - e;
    int idx = e + g; if (idx > e1 - 1) idx = e1 - 1;
    const int s = esrc[idx];
    const half8 hv = *(const half8*)(hp + (size_t)s * 64 + f8 * 8);
    const float m = (g < rem) ? 1.f : 0.f;
#pragma unroll
    for (int k = 0; k < 8; ++k) acc[k] = fmaf(m, (float)hv[k], acc[k]);
  }

  // reduce-scatter butterfly: each round sends the half the partner keeps.
  const bool gb0 = (g & 1) != 0;
  const float s0 = gb0 ? acc[0] : acc[1];
  const float s1 = gb0 ? acc[2] : acc[3];
  const float s2 = gb0 ? acc[4] : acc[5];
  const float s3 = gb0 ? acc[6] : acc[7];
  const float k0 = (gb0 ? acc[1] : acc[0]) + __shfl_xor(s0, 8);
  const float k1 = (gb0 ? acc[3] : acc[2]) + __shfl_xor(s1, 8);
  const float k2 = (gb0 ? acc[5] : acc[4]) + __shfl_xor(s2, 8);
  const float k3 = (gb0 ? acc[7] : acc[6]) + __shfl_xor(s3, 8);
  const bool gb1 = (g & 2) != 0;
  const float t0 = gb1 ? k0 : k1;
  const float t1 = gb1 ? k2 : k3;
  const float m0 = (gb1 ? k1 : k0) + __shfl_xor(t0, 16);
  const float m1 = (gb1 ? k3 : k2) + __shfl_xor(t1, 16);
  const bool gb2 = (g & 4) != 0;
  const float u0 = gb2 ? m0 : m1;
  float v = (gb2 ? m1 : m0) + __shfl_xor(u0, 32);

  v = v * vi + bv;
  if (apply_elu) v = (v > 0.f) ? v : (__expf(v) - 1.0f);
  out[(size_t)w * 64 + f] = (_Float16)v;
}

extern "C" void kernel_launch(void* const* d_in, const int* in_sizes, int n_in,
                              void* d_out, int out_size, void* d_ws, size_t ws_size,
                              hipStream_t stream) {
  const float* x  = (const float*)d_in[0];
  const int*   src = (const int*)d_in[1];
  const int*   dst = (const int*)d_in[2];
  const float* W0 = (const float*)d_in[3];
  const float* b0 = (const float*)d_in[4];
  const float* W1 = (const float*)d_in[5];
  const float* b1 = (const float*)d_in[6];
  const float* W2 = (const float*)d_in[7];
  const float* b2 = (const float*)d_in[8];
  const float* Wl = (const float*)d_in[9];
  const float* bl = (const float*)d_in[10];

  const int N = in_sizes[0] / 128;
  const int E = in_sizes[1];
  const int NR = (N + RWID - 1) >> RW_SH;
  const int EPC = (((E + NCHUNK - 1) / NCHUNK) + 3) & ~3;
  const int EPCO = (((E + NCO - 1) / NCO) + 3) & ~3;

  int* wsp = (int*)d_ws;
  size_t off = 0;
  auto alloc = [&](size_t n) -> int* {   // 256B-aligned regions
    int* p = wsp + off;
    off += (n + 63) & ~(size_t)63;
    return p;
  };
  float*    invo       = (float*)alloc(N);
  float*    invi       = (float*)alloc(N);
  int*      rptr       = alloc((size_t)N + 1);
  int*      esrc       = alloc(E);
  int*      cntA       = alloc((size_t)NR * NCHUNK);
  int*      base_rel   = alloc((size_t)NR * NCHUNK);
  int*      cntR       = alloc(NR);
  int*      rangeStart = alloc((size_t)NR + 1);
  int*      bucket     = alloc(E);
  int*      slab       = alloc((size_t)NCO * (N >> 1));  // u16-packed
  _Float16* hP         = (_Float16*)alloc((size_t)N * 32);  // N x 64 f16
  _Float16* hA         = (_Float16*)alloc((size_t)N * 32);  // N x 64 f16
  _Float16* WT0        = (_Float16*)alloc(64 * 128 / 2);
  _Float16* WT1        = (_Float16*)alloc(64 * 64 / 2);
  _Float16* WT2        = (_Float16*)alloc(64 * 64 / 2);
  _Float16* WTl        = (_Float16*)alloc(64 * 64 / 2);
  (void)ws_size; (void)n_in; (void)out_size;

  const int gAgg = (N + 3) / 4;
  const int gGemm = (N + 63) / 64;
  const int gInvo = ((N >> 1) + WG - 1) / WG;

  // K1: coarse_hist || dego_hist || wtrans
  setup1_kernel<<<NCHUNK + NRO * NCO + 4, WG, 0, stream>>>(
      src, dst, cntA, slab, W0, W1, W2, Wl, WT0, WT1, WT2, WTl, NR, N, E, EPC, EPCO);
  // K2: chunkscan || dego_reduce->invo
  setup2_kernel<<<NR + gInvo, WG, 0, stream>>>(cntA, base_rel, cntR, slab, invo, NR, N);
  // K3: range scan
  rangescan_kernel<<<1, WG, 0, stream>>>(cntR, rangeStart, rptr, NR, N, E);
  // K4: bucket scatter
  bucket_kernel<<<NCHUNK, WG, 0, stream>>>(src, dst, base_rel, rangeStart, bucket, NR, E, EPC);
  // K5: CSR finalize (+invi)
  csr_kernel<<<NR, WG, 0, stream>>>(bucket, rangeStart, rptr, invi, esrc, N);

  // layer 0: (x@W0)*invo -> agg -> *invi+b0 -> elu
  gemm_conv_mfma<128, false><<<gGemm, 256, 0, stream>>>(x, WT0, invo, hP, N);
  agg_kernel<<<gAgg, 256, 0, stream>>>(hP, rptr, esrc, invi, b0, hA, N, 1);
  // layer 1
  gemm_conv_mfma<64, true><<<gGemm, 256, 0, stream>>>(hA, WT1, invo, hP, N);
  agg_kernel<<<gAgg, 256, 0, stream>>>(hP, rptr, esrc, invi, b1, hA, N, 1);
  // layer 2 (+ fused elu ahead of the linear head)
  gemm_conv_mfma<64, true><<<gGemm, 256, 0, stream>>>(hA, WT2, invo, hP, N);
  agg_kernel<<<gAgg, 256, 0, stream>>>(hP, rptr, esrc, invi, b2, hA, N, 1);
  // head: elu(h2) @ Wl + bl
  gemm_head_mfma<<<gGemm, 256, 0, stream>>>(hA, WTl, bl, (float*)d_out, N);
}

// Round 14
// 240.831 us; speedup vs baseline: 1.1592x; 1.0086x over previous
//
#include <hip/hip_runtime.h>
#include <hip/hip_fp16.h>
#include <cstdint>
#include <cstddef>

// ---------------------------------------------------------------------------
// GCN: 3x GraphConv(norm='both') + linear head, fp32 in/out.
// Round 14 = round 13 +:
//  - K3' = rangescan(1 blk) || gemm0(1563 blk): layer-0 GEMM depends only on
//    WT0+invo (ready after K2), so it hides under the CSR-build tail instead
//    of running serially after csr.
//  - dego_hist: BPRO 12512->32000 (62.5KB LDS u16-packed), NRO 8->4 ->
//    src re-reads 51MB -> 25.6MB.
// Agg frozen (round-8 form): ~41G line-touches/s = L2 request ceiling,
// FETCH 82MB = compulsory per-XCD floor (r9/r10/r12 all failed to beat it).
// ---------------------------------------------------------------------------

#define WG 256
static constexpr int NCHUNK = 512;   // edge chunks for dst bucketing
static constexpr int RW_SH  = 7;     // range width = 128 nodes (dst>>7)
static constexpr int RWID   = 1 << RW_SH;
static constexpr int BPRO   = 32000; // nodes per dego range (packed u16, 62.5KB)
static constexpr int NRO    = 4;     // dego ranges (4*32000 >= 100000)
static constexpr int NCO    = 64;    // edge chunks for dego histogram

typedef _Float16 half8 __attribute__((ext_vector_type(8)));
typedef _Float16 half2v __attribute__((ext_vector_type(2)));
typedef float f32x4 __attribute__((ext_vector_type(4)));

__device__ __forceinline__ int block_scan_excl(int v, int tid, int* sd, int& total) {
  sd[tid] = v;
  __syncthreads();
  for (int off = 1; off < 256; off <<= 1) {
    int t = (tid >= off) ? sd[tid - off] : 0;
    __syncthreads();
    sd[tid] += t;
    __syncthreads();
  }
  int incl = sd[tid];
  total = sd[255];
  __syncthreads();
  return incl - v;
}

// --- K1: coarse_hist (dst) || dego_hist (src) || wtrans ---------------------
__global__ __launch_bounds__(WG) void setup1_kernel(const int* __restrict__ src,
                                                    const int* __restrict__ dst,
                                                    int* __restrict__ cntA,
                                                    int* __restrict__ slab,
                                                    const float* __restrict__ W0,
                                                    const float* __restrict__ W1,
                                                    const float* __restrict__ W2,
                                                    const float* __restrict__ Wl,
                                                    _Float16* __restrict__ T0,
                                                    _Float16* __restrict__ T1,
                                                    _Float16* __restrict__ T2,
                                                    _Float16* __restrict__ Tl,
                                                    int NR, int N, int E, int EPC, int EPCO) {
  __shared__ int smem[BPRO / 2];   // 62.5KB union: cnt[<=1024] / h[BPRO/2]
  const int b = blockIdx.x, tid = threadIdx.x;

  if (b < NCHUNK) {
    // ---- coarse histogram of dst ranges for chunk b ----
    int* cnt = smem;
    for (int i = tid; i < NR; i += WG) cnt[i] = 0;
    __syncthreads();
    const int base = b * EPC;
    const int nv4 = EPC >> 2;
    const int4* d4 = (const int4*)(dst + base);
    for (int i = tid; i < nv4; i += WG) {
      const int e = base + (i << 2);
      if (e + 3 < E) {
        const int4 v = d4[i];
        atomicAdd(&cnt[v.x >> RW_SH], 1);
        atomicAdd(&cnt[v.y >> RW_SH], 1);
        atomicAdd(&cnt[v.z >> RW_SH], 1);
        atomicAdd(&cnt[v.w >> RW_SH], 1);
      } else {
        for (int j = 0; j < 4; ++j) {
          const int ee = e + j;
          if (ee < E) atomicAdd(&cnt[dst[ee] >> RW_SH], 1);
        }
      }
    }
    __syncthreads();
    for (int i = tid; i < NR; i += WG) cntA[i * NCHUNK + b] = cnt[i];
    return;
  }

  if (b < NCHUNK + NRO * NCO) {
    // ---- u16-packed dego histogram ----
    int* h = smem;
    const int bb = b - NCHUNK;
    const int rr = bb / NCO, cc = bb % NCO;
    for (int i = tid; i < (BPRO >> 3); i += WG) ((int4*)h)[i] = make_int4(0, 0, 0, 0);
    __syncthreads();
    const int lo = rr * BPRO;
    const int base = cc * EPCO;
    const int nv4 = EPCO >> 2;
    const int4* s4 = (const int4*)(src + base);
    for (int i = tid; i < nv4; i += WG) {
      const int e = base + (i << 2);
      if (e + 3 < E) {
        const int4 v = s4[i];
        unsigned x;
        x = (unsigned)(v.x - lo); if (x < (unsigned)BPRO) atomicAdd((unsigned*)&h[x >> 1], 1u << ((x & 1) << 4));
        x = (unsigned)(v.y - lo); if (x < (unsigned)BPRO) atomicAdd((unsigned*)&h[x >> 1], 1u << ((x & 1) << 4));
        x = (unsigned)(v.z - lo); if (x < (unsigned)BPRO) atomicAdd((unsigned*)&h[x >> 1], 1u << ((x & 1) << 4));
        x = (unsigned)(v.w - lo); if (x < (unsigned)BPRO) atomicAdd((unsigned*)&h[x >> 1], 1u << ((x & 1) << 4));
      } else {
        for (int j = 0; j < 4; ++j) {
          const int ee = e + j;
          if (ee < E) {
            const unsigned x = (unsigned)(src[ee] - lo);
            if (x < (unsigned)BPRO) atomicAdd((unsigned*)&h[x >> 1], 1u << ((x & 1) << 4));
          }
        }
      }
    }
    __syncthreads();
    const int NW = N >> 1;
    const int wbase = lo >> 1;
    int* srow = slab + (size_t)cc * NW;
    for (int i = tid; i < (BPRO >> 3); i += WG) {
      const int wg = wbase + (i << 2);
      if (wg + 3 < NW) {
        ((int4*)(srow + wg))[0] = ((const int4*)h)[i];
      } else {
        for (int j = 0; j < 4; ++j)
          if (wg + j < NW) srow[wg + j] = h[(i << 2) + j];
      }
    }
    return;
  }

  // ---- wtrans: WT[c][k] = (f16)W[k][c] ----
  const float* W; _Float16* T; int K;
  switch (b - (NCHUNK + NRO * NCO)) {
    case 0: W = W0; T = T0; K = 128; break;
    case 1: W = W1; T = T1; K = 64; break;
    case 2: W = W2; T = T2; K = 64; break;
    default: W = Wl; T = Tl; K = 64; break;
  }
  for (int i = tid; i < K * 64; i += WG) {
    const int k = i >> 6, c = i & 63;
    T[c * K + k] = (_Float16)W[i];
  }
}

// --- K2: chunkscan || dego_reduce -> invo ------------------------------------
__global__ __launch_bounds__(WG) void setup2_kernel(const int* __restrict__ cntA,
                                                    int* __restrict__ base_rel,
                                                    int* __restrict__ cntR,
                                                    const int* __restrict__ slab,
                                                    float* __restrict__ invo,
                                                    int NR, int N) {
  __shared__ int sd[256];
  const int b = blockIdx.x, tid = threadIdx.x;

  if (b < NR) {
    const int row = b * NCHUNK;
    int t0, t1;
    const int v0 = cntA[row + tid];
    const int e0 = block_scan_excl(v0, tid, sd, t0);
    base_rel[row + tid] = e0;
    const int v1 = cntA[row + 256 + tid];
    const int e1 = block_scan_excl(v1, tid, sd, t1);
    base_rel[row + 256 + tid] = t0 + e1;
    if (tid == 0) cntR[b] = t0 + t1;
    return;
  }

  const int NW = N >> 1;
  const int i = (b - NR) * WG + tid;
  if (i >= NW) return;
  unsigned s = 0;
#pragma unroll
  for (int c = 0; c < NCO; ++c) s += (unsigned)slab[(size_t)c * NW + i];
  int d0 = (int)(s & 0xffffu); if (d0 < 1) d0 = 1;
  int d1 = (int)(s >> 16);     if (d1 < 1) d1 = 1;
  *(float2*)(invo + 2 * i) = make_float2(rsqrtf((float)d0), rsqrtf((float)d1));
}

// --- shared gemm-conv body (bid-parameterized for co-scheduled launches) ----
template <int K, bool F16IN>
__device__ __forceinline__ void gemm_conv_body(int bid, const void* __restrict__ inv_,
                                               const _Float16* __restrict__ WT,
                                               const float* __restrict__ invo,
                                               _Float16* __restrict__ hP, int N) {
  const int tid = threadIdx.x;
  const int w = tid >> 6, l = tid & 63;
  const int rowA = bid * 64 + w * 16 + (l & 15);
  const int ar = (rowA < N) ? rowA : (N - 1);
  const int g8 = (l >> 4) * 8;

  f32x4 acc[4];
#pragma unroll
  for (int t = 0; t < 4; ++t) acc[t] = (f32x4){0.f, 0.f, 0.f, 0.f};

#pragma unroll
  for (int s = 0; s < K / 32; ++s) {
    const int kb = s * 32 + g8;
    half8 a;
    if constexpr (F16IN) {
      a = *(const half8*)((const _Float16*)inv_ + (size_t)ar * K + kb);
    } else {
      const float* in = (const float*)inv_;
      const float4 f0 = *(const float4*)(in + (size_t)ar * K + kb);
      const float4 f1 = *(const float4*)(in + (size_t)ar * K + kb + 4);
      a[0] = (_Float16)f0.x; a[1] = (_Float16)f0.y; a[2] = (_Float16)f0.z; a[3] = (_Float16)f0.w;
      a[4] = (_Float16)f1.x; a[5] = (_Float16)f1.y; a[6] = (_Float16)f1.z; a[7] = (_Float16)f1.w;
    }
#pragma unroll
    for (int t = 0; t < 4; ++t) {
      const half8 b = *(const half8*)(WT + (size_t)(16 * t + (l & 15)) * K + kb);
      acc[t] = __builtin_amdgcn_mfma_f32_16x16x32_f16(a, b, acc[t], 0, 0, 0);
    }
  }

  const int rbase = bid * 64 + w * 16 + (l >> 4) * 4;
#pragma unroll
  for (int r = 0; r < 4; ++r) {
    const int row = rbase + r;
    if (row < N) {
      const float sc = invo[row];
#pragma unroll
      for (int t = 0; t < 4; ++t)
        hP[(size_t)row * 64 + 16 * t + (l & 15)] = (_Float16)(acc[t][r] * sc);
    }
  }
}

// --- K3': rangescan (block 0) || layer-0 GEMM (blocks 1..) ------------------
__global__ __launch_bounds__(WG) void range_gemm0_kernel(const int* __restrict__ cntR,
                                                         int* __restrict__ rangeStart,
                                                         int* __restrict__ rptr,
                                                         const float* __restrict__ x,
                                                         const _Float16* __restrict__ WT0,
                                                         const float* __restrict__ invo,
                                                         _Float16* __restrict__ hP,
                                                         int NR, int N, int E) {
  __shared__ int sd[256];
  const int b = blockIdx.x, tid = threadIdx.x;
  if (b == 0) {
    int carry = 0;
    for (int base = 0; base < NR; base += 256) {
      const int idx = base + tid;
      const int v = (idx < NR) ? cntR[idx] : 0;
      int tot;
      const int e = block_scan_excl(v, tid, sd, tot);
      if (idx < NR) rangeStart[idx] = carry + e;
      carry += tot;
    }
    if (tid == 0) { rangeStart[NR] = E; rptr[N] = E; }
    return;
  }
  gemm_conv_body<128, false>(b - 1, x, WT0, invo, hP, N);
}

// --- K4: bucket scatter with LDS cursors, 4B packed entries -----------------
__global__ __launch_bounds__(WG) void bucket_kernel(const int* __restrict__ src,
                                                    const int* __restrict__ dst,
                                                    const int* __restrict__ base_rel,
                                                    const int* __restrict__ rangeStart,
                                                    int* __restrict__ bucket,
                                                    int NR, int E, int EPC) {
  __shared__ int cur[1024];
  const int c = blockIdx.x, tid = threadIdx.x;
  for (int i = tid; i < NR; i += WG) cur[i] = rangeStart[i] + base_rel[i * NCHUNK + c];
  __syncthreads();
  const int base = c * EPC;
  const int nv4 = EPC >> 2;
  const int4* s4 = (const int4*)(src + base);
  const int4* d4 = (const int4*)(dst + base);
  for (int i = tid; i < nv4; i += WG) {
    const int e = base + (i << 2);
    if (e + 3 < E) {
      const int4 sv = s4[i];
      const int4 dv = d4[i];
      int p;
      p = atomicAdd(&cur[dv.x >> RW_SH], 1); bucket[p] = (sv.x << RW_SH) | (dv.x & (RWID - 1));
      p = atomicAdd(&cur[dv.y >> RW_SH], 1); bucket[p] = (sv.y << RW_SH) | (dv.y & (RWID - 1));
      p = atomicAdd(&cur[dv.z >> RW_SH], 1); bucket[p] = (sv.z << RW_SH) | (dv.z & (RWID - 1));
      p = atomicAdd(&cur[dv.w >> RW_SH], 1); bucket[p] = (sv.w << RW_SH) | (dv.w & (RWID - 1));
    } else {
      for (int j = 0; j < 4; ++j) {
        const int ee = e + j;
        if (ee < E) {
          const int s = src[ee], d = dst[ee];
          const int p = atomicAdd(&cur[d >> RW_SH], 1);
          bucket[p] = (s << RW_SH) | (d & (RWID - 1));
        }
      }
    }
  }
}

// --- K5: per-range CSR finalize (rptr, invi, esrc) ---------------------------
__global__ __launch_bounds__(WG) void csr_kernel(const int* __restrict__ bucket,
                                                 const int* __restrict__ rangeStart,
                                                 int* __restrict__ rptr,
                                                 float* __restrict__ invi,
                                                 int* __restrict__ esrc, int N) {
  __shared__ int hist[RWID], sd[256];
  const int r = blockIdx.x, tid = threadIdx.x;
  const int s0 = rangeStart[r], s1 = rangeStart[r + 1];
  if (tid < RWID) hist[tid] = 0;
  __syncthreads();
  for (int e = s0 + tid; e < s1; e += WG) atomicAdd(&hist[bucket[e] & (RWID - 1)], 1);
  __syncthreads();
  const int v = (tid < RWID) ? hist[tid] : 0;
  int tot;
  const int excl = block_scan_excl(v, tid, sd, tot);
  const int node = (r << RW_SH) + tid;
  if (tid < RWID && node < N) {
    rptr[node] = s0 + excl;
    invi[node] = rsqrtf((float)((v < 1) ? 1 : v));
  }
  if (tid < RWID) hist[tid] = s0 + excl;
  __syncthreads();
  for (int e = s0 + tid; e < s1; e += WG) {
    const int pk = bucket[e];
    const int p = atomicAdd(&hist[pk & (RWID - 1)], 1);
    esrc[p] = pk >> RW_SH;
  }
}

// --- standalone conv GEMM (layers 1,2) --------------------------------------
template <int K, bool F16IN>
__global__ __launch_bounds__(256) void gemm_conv_mfma(const void* __restrict__ inv_,
                                                      const _Float16* __restrict__ WT,
                                                      const float* __restrict__ invo,
                                                      _Float16* __restrict__ hP, int N) {
  gemm_conv_body<K, F16IN>(blockIdx.x, inv_, WT, invo, hP, N);
}

// --- MFMA head GEMM (f16 in): out[r][c] = sum_k in[r][k] W[k][c] + bias[c] --
__global__ __launch_bounds__(256) void gemm_head_mfma(const _Float16* __restrict__ in,
                                                      const _Float16* __restrict__ WT,
                                                      const float* __restrict__ bias,
                                                      float* __restrict__ out, int N) {
  constexpr int K = 64;
  const int tid = threadIdx.x;
  const int w = tid >> 6, l = tid & 63;
  const int rowA = blockIdx.x * 64 + w * 16 + (l & 15);
  const int ar = (rowA < N) ? rowA : (N - 1);
  const int g8 = (l >> 4) * 8;

  f32x4 acc[4];
#pragma unroll
  for (int t = 0; t < 4; ++t) acc[t] = (f32x4){0.f, 0.f, 0.f, 0.f};

#pragma unroll
  for (int s = 0; s < K / 32; ++s) {
    const int kb = s * 32 + g8;
    const half8 a = *(const half8*)(in + (size_t)ar * K + kb);
#pragma unroll
    for (int t = 0; t < 4; ++t) {
      const half8 b = *(const half8*)(WT + (size_t)(16 * t + (l & 15)) * K + kb);
      acc[t] = __builtin_amdgcn_mfma_f32_16x16x32_f16(a, b, acc[t], 0, 0, 0);
    }
  }

  const int rbase = blockIdx.x * 64 + w * 16 + (l >> 4) * 4;
#pragma unroll
  for (int r = 0; r < 4; ++r) {
    const int row = rbase + r;
    if (row < N) {
#pragma unroll
      for (int t = 0; t < 4; ++t) {
        const int c = 16 * t + (l & 15);
        out[(size_t)row * 64 + c] = acc[t][r] + bias[c];
      }
    }
  }
}

// --- CSR gather aggregation, 8 lanes per row (round-8 form, frozen) ---------
__global__ __launch_bounds__(256) void agg_kernel(const _Float16* __restrict__ hp,
                                                  const int* __restrict__ rptr,
                                                  const int* __restrict__ esrc,
                                                  const float* __restrict__ invin,
                                                  const float* __restrict__ bias,
                                                  _Float16* __restrict__ out, int N,
                                                  int apply_elu) {
  const int w = (blockIdx.x * 256 + threadIdx.x) >> 6;  // one wave per dst node
  const int lane = threadIdx.x & 63;
  const int g = lane >> 3;     // edge slot 0..7
  const int f8 = lane & 7;     // feature octet
  if (w >= N) return;
  const int e0 = rptr[w];
  const int e1 = rptr[w + 1];
  const int f = f8 * 8 + g;
  const float vi = invin[w];
  const float bv = bias[f];

  float acc[8];
#pragma unroll
  for (int k = 0; k < 8; ++k) acc[k] = 0.f;

  int e = e0;
  for (; e + 16 <= e1; e += 16) {   // 2 gathers in flight, fdot2 accumulate
    const int sA = esrc[e + g];
    const int sB = esrc[e + 8 + g];
    const half8 hA8 = *(const half8*)(hp + (size_t)sA * 64 + f8 * 8);
    const half8 hB8 = *(const half8*)(hp + (size_t)sB * 64 + f8 * 8);
#if __has_builtin(__builtin_amdgcn_fdot2)
    const half2v one2 = {(_Float16)1.0f, (_Float16)1.0f};
#pragma unroll
    for (int k = 0; k < 8; ++k) {
      half2v p; p[0] = hA8[k]; p[1] = hB8[k];
      acc[k] = __builtin_amdgcn_fdot2(p, one2, acc[k], false);
    }
#else
#pragma unroll
    for (int k = 0; k < 8; ++k) acc[k] += (float)hA8[k] + (float)hB8[k];
#endif
  }
  for (; e + 8 <= e1; e += 8) {
    const int s = esrc[e + g];
    const half8 hv = *(const half8*)(hp + (size_t)s * 64 + f8 * 8);
#pragma unroll
    for (int k = 0; k < 8; ++k) acc[k] += (float)hv[k];
  }
  if (e < e1) {                      // masked tail group
    const int rem = e1 - e;
    int idx = e + g; if (idx > e1 - 1) idx = e1 - 1;
    const int s = esrc[idx];
    const half8 hv = *(const half8*)(hp + (size_t)s * 64 + f8 * 8);
    const float m = (g < rem) ? 1.f : 0.f;
#pragma unroll
    for (int k = 0; k < 8; ++k) acc[k] = fmaf(m, (float)hv[k], acc[k]);
  }

  // reduce-scatter butterfly: each round sends the half the partner keeps.
  const bool gb0 = (g & 1) != 0;
  const float s0 = gb0 ? acc[0] : acc[1];
  const float s1 = gb0 ? acc[2] : acc[3];
  const float s2 = gb0 ? acc[4] : acc[5];
  const float s3 = gb0 ? acc[6] : acc[7];
  const float k0 = (gb0 ? acc[1] : acc[0]) + __shfl_xor(s0, 8);
  const float k1 = (gb0 ? acc[3] : acc[2]) + __shfl_xor(s1, 8);
  const float k2 = (gb0 ? acc[5] : acc[4]) + __shfl_xor(s2, 8);
  const float k3 = (gb0 ? acc[7] : acc[6]) + __shfl_xor(s3, 8);
  const bool gb1 = (g & 2) != 0;
  const float t0 = gb1 ? k0 : k1;
  const float t1 = gb1 ? k2 : k3;
  const float m0 = (gb1 ? k1 : k0) + __shfl_xor(t0, 16);
  const float m1 = (gb1 ? k3 : k2) + __shfl_xor(t1, 16);
  const bool gb2 = (g & 4) != 0;
  const float u0 = gb2 ? m0 : m1;
  float v = (gb2 ? m1 : m0) + __shfl_xor(u0, 32);

  v = v * vi + bv;
  if (apply_elu) v = (v > 0.f) ? v : (__expf(v) - 1.0f);
  out[(size_t)w * 64 + f] = (_Float16)v;
}

extern "C" void kernel_launch(void* const* d_in, const int* in_sizes, int n_in,
                              void* d_out, int out_size, void* d_ws, size_t ws_size,
                              hipStream_t stream) {
  const float* x  = (const float*)d_in[0];
  const int*   src = (const int*)d_in[1];
  const int*   dst = (const int*)d_in[2];
  const float* W0 = (const float*)d_in[3];
  const float* b0 = (const float*)d_in[4];
  const float* W1 = (const float*)d_in[5];
  const float* b1 = (const float*)d_in[6];
  const float* W2 = (const float*)d_in[7];
  const float* b2 = (const float*)d_in[8];
  const float* Wl = (const float*)d_in[9];
  const float* bl = (const float*)d_in[10];

  const int N = in_sizes[0] / 128;
  const int E = in_sizes[1];
  const int NR = (N + RWID - 1) >> RW_SH;
  const int EPC = (((E + NCHUNK - 1) / NCHUNK) + 3) & ~3;
  const int EPCO = (((E + NCO - 1) / NCO) + 3) & ~3;

  int* wsp = (int*)d_ws;
  size_t off = 0;
  auto alloc = [&](size_t n) -> int* {   // 256B-aligned regions
    int* p = wsp + off;
    off += (n + 63) & ~(size_t)63;
    return p;
  };
  float*    invo       = (float*)alloc(N);
  float*    invi       = (float*)alloc(N);
  int*      rptr       = alloc((size_t)N + 1);
  int*      esrc       = alloc(E);
  int*      cntA       = alloc((size_t)NR * NCHUNK);
  int*      base_rel   = alloc((size_t)NR * NCHUNK);
  int*      cntR       = alloc(NR);
  int*      rangeStart = alloc((size_t)NR + 1);
  int*      bucket     = alloc(E);
  int*      slab       = alloc((size_t)NCO * (N >> 1));  // u16-packed
  _Float16* hP         = (_Float16*)alloc((size_t)N * 32);  // N x 64 f16
  _Float16* hA         = (_Float16*)alloc((size_t)N * 32);  // N x 64 f16
  _Float16* WT0        = (_Float16*)alloc(64 * 128 / 2);
  _Float16* WT1        = (_Float16*)alloc(64 * 64 / 2);
  _Float16* WT2        = (_Float16*)alloc(64 * 64 / 2);
  _Float16* WTl        = (_Float16*)alloc(64 * 64 / 2);
  (void)ws_size; (void)n_in; (void)out_size;

  const int gAgg = (N + 3) / 4;
  const int gGemm = (N + 63) / 64;
  const int gInvo = ((N >> 1) + WG - 1) / WG;

  // K1: coarse_hist || dego_hist || wtrans
  setup1_kernel<<<NCHUNK + NRO * NCO + 4, WG, 0, stream>>>(
      src, dst, cntA, slab, W0, W1, W2, Wl, WT0, WT1, WT2, WTl, NR, N, E, EPC, EPCO);
  // K2: chunkscan || dego_reduce->invo
  setup2_kernel<<<NR + gInvo, WG, 0, stream>>>(cntA, base_rel, cntR, slab, invo, NR, N);
  // K3': rangescan || layer-0 GEMM (needs only WT0+invo)
  range_gemm0_kernel<<<1 + gGemm, WG, 0, stream>>>(cntR, rangeStart, rptr, x, WT0, invo, hP, NR, N, E);
  // K4: bucket scatter
  bucket_kernel<<<NCHUNK, WG, 0, stream>>>(src, dst, base_rel, rangeStart, bucket, NR, E, EPC);
  // K5: CSR finalize (+invi)
  csr_kernel<<<NR, WG, 0, stream>>>(bucket, rangeStart, rptr, invi, esrc, N);

  // layer 0 agg (gemm0 already done in K3')
  agg_kernel<<<gAgg, 256, 0, stream>>>(hP, rptr, esrc, invi, b0, hA, N, 1);
  // layer 1
  gemm_conv_mfma<64, true><<<gGemm, 256, 0, stream>>>(hA, WT1, invo, hP, N);
  agg_kernel<<<gAgg, 256, 0, stream>>>(hP, rptr, esrc, invi, b1, hA, N, 1);
  // layer 2 (+ fused elu ahead of the linear head)
  gemm_conv_mfma<64, true><<<gGemm, 256, 0, stream>>>(hA, WT2, invo, hP, N);
  agg_kernel<<<gAgg, 256, 0, stream>>>(hP, rptr, esrc, invi, b2, hA, N, 1);
  // head: elu(h2) @ Wl + bl
  gemm_head_mfma<<<gGemm, 256, 0, stream>>>(hA, WTl, bl, (float*)d_out, N);
}